// Round 1
// baseline (328.985 us; speedup 1.0000x reference)
//
#include <hip/hip_runtime.h>
#include <math.h>

#define CIN_    512
#define COUT_   512
#define LATENT_ 512
#define NB_     8
#define HH_     64
#define WW_     64

typedef float f32x16 __attribute__((ext_vector_type(16)));
typedef short bf16x8v __attribute__((ext_vector_type(8)));

__device__ inline unsigned short f2bf(float f) {
    union { float f; unsigned u; } v; v.f = f;
    unsigned r = v.u + 0x7fffu + ((v.u >> 16) & 1u);
    return (unsigned short)(r >> 16);
}

// Async global->LDS 16B copy. LDS dest must be wave-uniform base; HW adds lane*16.
__device__ __forceinline__ void gl_lds16(const void* g, void* l) {
    __builtin_amdgcn_global_load_lds(
        (const __attribute__((address_space(1))) unsigned int*)g,
        (__attribute__((address_space(3))) unsigned int*)l,
        16, 0, 0);
}

// ============ K1: fused wsq (blocks 0..1023) + wprep (1024..1311) + style (1312..1319)
// All three depend only on raw inputs.
__global__ __launch_bounds__(256) void prep1(
    const float* __restrict__ w, const float* __restrict__ dlat,
    const float* __restrict__ mw, const float* __restrict__ mb,
    float* __restrict__ wsq, unsigned short* __restrict__ wb,
    float* __restrict__ s)
{
    __shared__ float smem[16 * 521];   // wprep transpose buffer; style reuses [0..511]
    const float RC_W = 0.0147313912747197f;   // 1/sqrt(9*512)
    const float RC_S = 0.0441941738241592f;   // 1/sqrt(512)
    int b = blockIdx.x;
    int t = threadIdx.x;

    if (b < 1024) {
        // ---- wsq[ci][co] = sum_tap w^2 (fp32, exact demod) ----
        int idx = b * 256 + t;
        float acc = 0.f;
#pragma unroll
        for (int tap = 0; tap < 9; ++tap) {
            float v = w[tap * (CIN_ * COUT_) + idx];
            acc += v * v;
        }
        wsq[idx] = acc;
    } else if (b < 1312) {
        // ---- wprep: wb[tap][cb][co 512][ci16] = w[tap][ci][co]*RC_W (bf16, transposed)
        int bb  = b - 1024;
        int tap = bb / 32;
        int cb  = bb % 32;
        for (int idx = t; idx < 16 * 512; idx += 256) {
            int ci = idx >> 9;
            int co = idx & 511;
            smem[ci * 521 + co] = w[((size_t)tap * 512 + cb * 16 + ci) * 512 + co];
        }
        __syncthreads();
        unsigned short* dst = wb + (size_t)(tap * 32 + cb) * 512 * 16;
        for (int idx = t; idx < 16 * 512; idx += 256) {
            int co = idx >> 4;
            int ci = idx & 15;
            dst[idx] = f2bf(smem[ci * 521 + co] * RC_W);
        }
    } else {
        // ---- style: s[n][ci] = dlat . (mw*RC_S) + mb + 1 ----
        int n = b - 1312;
        for (int i = t; i < LATENT_; i += 256) smem[i] = dlat[n * LATENT_ + i];
        __syncthreads();
        for (int ci = t; ci < CIN_; ci += 256) {
            float acc = 0.f;
            for (int l = 0; l < LATENT_; ++l)
                acc += smem[l] * mw[l * CIN_ + ci];
            s[n * CIN_ + ci] = acc * RC_S + mb[ci] + 1.0f;
        }
    }
}

// ============ K2: fused demod (blocks 0..7) + xprep (8..16903)
// xprep: xt[n][cb][hp 66][wp 66][ci16] bf16 = x*s with zero-padded halo.
// Coalesced: stage 16ci x 64gw row-group via float4, LDS transpose (stride 67).
__global__ __launch_bounds__(256) void prep2(
    const float* __restrict__ x, const float* __restrict__ s,
    const float* __restrict__ wsq, float* __restrict__ dmod,
    unsigned short* __restrict__ xt)
{
    __shared__ float smem[16 * 67 + 16];   // 1088 floats; demod uses [0..511]
    int b = blockIdx.x;
    int t = threadIdx.x;

    if (b < 8) {
        // ---- demod: d[n][co] = rsqrt(RC_W^2 * sum_ci s^2 * wsq + 1e-8) ----
        const float RCW2 = 1.0f / 4608.0f;
        int n = b;
        for (int i = t; i < CIN_; i += 256) { float v = s[n * CIN_ + i]; smem[i] = v * v; }
        __syncthreads();
        for (int co = t; co < COUT_; co += 256) {
            float acc = 0.f;
            for (int ci = 0; ci < CIN_; ++ci)
                acc += smem[ci] * wsq[ci * COUT_ + co];
            dmod[n * COUT_ + co] = rsqrtf(RCW2 * acc + 1e-8f);
        }
    } else {
        int bb = b - 8;                  // n*32*66 + cb*66 + hp
        int hp = bb % 66;
        int cb = (bb / 66) % 32;
        int n  = bb / (66 * 32);
        int gh = hp - 1;
        bool rowok = (gh >= 0) && (gh < HH_);

        if (t < 16) smem[16 * 67 + t] = s[n * CIN_ + cb * 16 + t];
        if (rowok) {
            // 16 ci x 16 float4 = 256 threads, one float4 each (coalesced 256B/row)
            const float* src = &x[(((size_t)n * CIN_ + cb * 16) * HH_ + gh) * WW_];
            int ci = t >> 4;
            int g0 = (t & 15) * 4;
            float4 v = *(const float4*)&src[(size_t)ci * (HH_ * WW_) + g0];
            float* dstl = &smem[ci * 67 + g0];
            dstl[0] = v.x; dstl[1] = v.y; dstl[2] = v.z; dstl[3] = v.w;
        }
        __syncthreads();

        unsigned short* dst = xt + (((size_t)(n * 32 + cb) * 66 + hp) * 66) * 16;
        // 1056 u16 = 528 ushort2, coalesced
        for (int p = t; p < 528; p += 256) {
            int e  = p * 2;
            int wp = e >> 4;
            int ci = e & 15;
            int gw = wp - 1;
            float v0 = 0.f, v1 = 0.f;
            if (rowok && gw >= 0 && gw < WW_) {
                v0 = smem[ci * 67 + gw]       * smem[16 * 67 + ci];
                v1 = smem[(ci + 1) * 67 + gw] * smem[16 * 67 + ci + 1];
            }
            ushort2 o2; o2.x = f2bf(v0); o2.y = f2bf(v1);
            *(ushort2*)&dst[e] = o2;
        }
    }
}

// ============ main conv: implicit GEMM on 32x32x16 bf16 MFMA
// block: M=128 spatial (8 rows x 16 cols patch), N=128 co; 4 waves, each 64x64.
// R1 change: staging via __builtin_amdgcn_global_load_lds width=16 (async DMA,
// no VGPR round-trip). Both LDS destinations are linear (xs[li*8], ws[tap*2048+t*8])
// = wave-uniform base + lane*16B, the required gload_lds pattern.
__global__ __launch_bounds__(256) void conv_mfma(
    const unsigned short* __restrict__ xt,
    const unsigned short* __restrict__ wb,
    const float* __restrict__ dmod,
    float* __restrict__ out)
{
    __shared__ __align__(16) union {
        struct { unsigned short xs[2880]; unsigned short ws[18432]; } s;  // 42624 B
        float o[64 * 129];                                                // 33024 B
    } sm;

    int b   = blockIdx.x;
    int cot = b & 3;
    int wt_ = (b >> 2) & 3;
    int ht  = (b >> 4) & 7;
    int n   = b >> 7;
    int h0 = ht * 8, w0 = wt_ * 16, co0 = cot * 128;

    int t    = threadIdx.x;
    int wv   = t >> 6, lane = t & 63;
    int mh   = wv >> 1, nh = wv & 1;
    int l5   = lane & 31, half = lane >> 5;

    f32x16 acc[2][2];
#pragma unroll
    for (int ms = 0; ms < 2; ++ms)
#pragma unroll
        for (int ns = 0; ns < 2; ++ns)
#pragma unroll
            for (int i = 0; i < 16; ++i) acc[ms][ns][i] = 0.f;

    for (int cb = 0; cb < 32; ++cb) {
        // stage x halo tile: 10 rows x 18 wp x 16 ci (360 x 16B), async to LDS.
        // xs layout is linear in li: xs[li*8] since row*288+off*8 == li*8.
        const unsigned short* xb = xt + (((size_t)(n * 32 + cb) * 66 + h0) * 66 + w0) * 16;
        for (int li = t; li < 360; li += 256) {
            int row = li / 36;
            int off = li - row * 36;
            // (li - lane) is wave-uniform: chunk base for this wave's 64x16B slab.
            gl_lds16(&xb[row * 1056 + off * 8], &sm.s.xs[(li - lane) * 8]);
        }
        // stage weights: 9 taps x 128 co x 16 ci (each tap = 256 x 16B), async.
        const unsigned short* wbb = wb + ((size_t)cb * 512 + co0) * 16;
#pragma unroll
        for (int tap = 0; tap < 9; ++tap) {
            gl_lds16(&wbb[(size_t)tap * 32 * 512 * 16 + t * 8],
                     &sm.s.ws[tap * 2048 + wv * 512]);
        }
        __syncthreads();   // compiler emits s_waitcnt vmcnt(0) before s_barrier

#pragma unroll
        for (int tap = 0; tap < 9; ++tap) {
            int kh = tap / 3, kw = tap - 3 * (tap / 3);
            bf16x8v bfr[2], afr[2];
#pragma unroll
            for (int ns = 0; ns < 2; ++ns) {
                int co_l = nh * 64 + ns * 32 + l5;
                bfr[ns] = *(const bf16x8v*)&sm.s.ws[tap * 2048 + co_l * 16 + half * 8];
            }
#pragma unroll
            for (int ms = 0; ms < 2; ++ms) {
                int pr = mh * 4 + ms * 2 + (l5 >> 4);
                int pc = l5 & 15;
                int pos = (pr + kh) * 18 + (pc + kw);
                afr[ms] = *(const bf16x8v*)&sm.s.xs[pos * 16 + half * 8];
            }
#pragma unroll
            for (int ms = 0; ms < 2; ++ms)
#pragma unroll
                for (int ns = 0; ns < 2; ++ns)
                    acc[ms][ns] = __builtin_amdgcn_mfma_f32_32x32x16_bf16(
                        afr[ms], bfr[ns], acc[ms][ns], 0, 0, 0);
        }
        __syncthreads();
    }

    // epilogue: demod + LDS transpose + coalesced float4 stores (2 passes)
    for (int p = 0; p < 2; ++p) {
        __syncthreads();
        int co_l = nh * 64 + p * 32 + l5;
        int bco  = nh * 32 + l5;
        float dv = dmod[n * COUT_ + co0 + co_l];
#pragma unroll
        for (int ms = 0; ms < 2; ++ms) {
#pragma unroll
            for (int reg = 0; reg < 16; ++reg) {
                int ml = (reg & 3) + 8 * (reg >> 2) + 4 * half;
                int pr = mh * 4 + ms * 2 + (ml >> 4);
                int pc = ml & 15;
                sm.o[bco * 129 + pr * 16 + pc] = acc[ms][p][reg] * dv;
            }
        }
        __syncthreads();
        for (int j = t; j < 2048; j += 256) {
            int wq = j & 3;
            int pairidx = j >> 2;
            int row  = pairidx & 7;
            int bco2 = pairidx >> 3;
            int co = (bco2 >> 5) * 64 + p * 32 + (bco2 & 31);
            const float* src = &sm.o[bco2 * 129 + row * 16 + wq * 4];
            float4 v = make_float4(src[0], src[1], src[2], src[3]);
            *(float4*)&out[(((size_t)n * COUT_ + co0 + co) * HH_ + h0 + row) * WW_ + w0 + wq * 4] = v;
        }
    }
}

extern "C" void kernel_launch(void* const* d_in, const int* in_sizes, int n_in,
                              void* d_out, int out_size, void* d_ws, size_t ws_size,
                              hipStream_t stream) {
    const float* x    = (const float*)d_in[0];
    const float* dlat = (const float*)d_in[1];
    const float* w    = (const float*)d_in[2];
    const float* mw   = (const float*)d_in[3];
    const float* mb   = (const float*)d_in[4];
    float* out = (float*)d_out;

    char* ws = (char*)d_ws;
    float* s    = (float*)(ws);                       // 4096 f
    float* dmod = (float*)(ws + 16384);               // 4096 f
    float* wsq  = (float*)(ws + 32768);               // 262144 f
    unsigned short* xt = (unsigned short*)(ws + 1081344);    // 17,842,176 u16
    unsigned short* wb = (unsigned short*)(ws + 36765696);   // 2,359,296 u16

    prep1<<<1320, 256, 0, stream>>>(w, dlat, mw, mb, wsq, wb, s);
    prep2<<<8 + NB_ * 32 * 66, 256, 0, stream>>>(x, s, wsq, dmod, xt);
    conv_mfma<<<1024, 256, 0, stream>>>(xt, wb, dmod, out);
}

// Round 2
// 292.405 us; speedup vs baseline: 1.1251x; 1.1251x over previous
//
#include <hip/hip_runtime.h>
#include <math.h>

#define CIN_    512
#define COUT_   512
#define LATENT_ 512
#define NB_     8
#define HH_     64
#define WW_     64

typedef float f32x16 __attribute__((ext_vector_type(16)));
typedef short bf16x8v __attribute__((ext_vector_type(8)));

__device__ inline unsigned short f2bf(float f) {
    union { float f; unsigned u; } v; v.f = f;
    unsigned r = v.u + 0x7fffu + ((v.u >> 16) & 1u);
    return (unsigned short)(r >> 16);
}

// Async global->LDS 16B copy. LDS dest must be wave-uniform base; HW adds lane*16.
__device__ __forceinline__ void gl_lds16(const void* g, void* l) {
    __builtin_amdgcn_global_load_lds(
        (const __attribute__((address_space(1))) unsigned int*)g,
        (__attribute__((address_space(3))) unsigned int*)l,
        16, 0, 0);
}

// ============ K1: fused wsq (blocks 0..1023) + wprep (1024..1311) + style (1312..1375)
// R2: style parallelized 8 -> 64 blocks (8 n x 8 ci-chunks), 4 waves split the
// 512-long L-reduction into 4x128 slices + LDS reduce. Kills the 512-iteration
// serial latency tail that left 248 CUs idle.
__global__ __launch_bounds__(256) void prep1(
    const float* __restrict__ w, const float* __restrict__ dlat,
    const float* __restrict__ mw, const float* __restrict__ mb,
    float* __restrict__ wsq, unsigned short* __restrict__ wb,
    float* __restrict__ s)
{
    __shared__ float smem[16 * 521];   // wprep transpose buffer; style reuses [0..767]
    const float RC_W = 0.0147313912747197f;   // 1/sqrt(9*512)
    const float RC_S = 0.0441941738241592f;   // 1/sqrt(512)
    int b = blockIdx.x;
    int t = threadIdx.x;

    if (b < 1024) {
        // ---- wsq[ci][co] = sum_tap w^2 (fp32, exact demod) ----
        int idx = b * 256 + t;
        float acc = 0.f;
#pragma unroll
        for (int tap = 0; tap < 9; ++tap) {
            float v = w[tap * (CIN_ * COUT_) + idx];
            acc += v * v;
        }
        wsq[idx] = acc;
    } else if (b < 1312) {
        // ---- wprep: wb[tap][cb][co 512][ci16] = w[tap][ci][co]*RC_W (bf16, transposed)
        int bb  = b - 1024;
        int tap = bb / 32;
        int cb  = bb % 32;
        for (int idx = t; idx < 16 * 512; idx += 256) {
            int ci = idx >> 9;
            int co = idx & 511;
            smem[ci * 521 + co] = w[((size_t)tap * 512 + cb * 16 + ci) * 512 + co];
        }
        __syncthreads();
        unsigned short* dst = wb + (size_t)(tap * 32 + cb) * 512 * 16;
        for (int idx = t; idx < 16 * 512; idx += 256) {
            int co = idx >> 4;
            int ci = idx & 15;
            dst[idx] = f2bf(smem[ci * 521 + co] * RC_W);
        }
    } else {
        // ---- style: s[n][ci] = dlat . (mw*RC_S) + mb + 1 ----
        // 64 blocks: n = bb>>3, ci-chunk of 64 = bb&7. 4 waves x 128-L slices.
        int bb  = b - 1312;
        int n   = bb >> 3;
        int ci0 = (bb & 7) * 64;
        for (int i = t; i < LATENT_; i += 256) smem[i] = dlat[n * LATENT_ + i];
        __syncthreads();
        int cil  = t & 63;          // ci within chunk (coalesced across lanes)
        int part = t >> 6;          // wave id: L-slice
        const float* mwp = mw + ci0 + cil;
        float a0 = 0.f, a1 = 0.f;
        int l0 = part * 128;
#pragma unroll 4
        for (int l = l0; l < l0 + 128; l += 2) {
            a0 += smem[l]     * mwp[(size_t)l * CIN_];
            a1 += smem[l + 1] * mwp[(size_t)(l + 1) * CIN_];
        }
        smem[512 + part * 64 + cil] = a0 + a1;
        __syncthreads();
        if (t < 64) {
            float r = smem[512 + t] + smem[576 + t] + smem[640 + t] + smem[704 + t];
            s[n * CIN_ + ci0 + t] = r * RC_S + mb[ci0 + t] + 1.0f;
        }
    }
}

// ============ K2: fused demod (blocks 0..63) + xprep (64..16959)
// R2: demod parallelized 8 -> 64 blocks (same 4-wave split-reduce as style);
// xprep stores widened ushort2 -> ushort4 (8B/lane).
__global__ __launch_bounds__(256) void prep2(
    const float* __restrict__ x, const float* __restrict__ s,
    const float* __restrict__ wsq, float* __restrict__ dmod,
    unsigned short* __restrict__ xt)
{
    __shared__ float smem[16 * 67 + 16];   // 1088 floats; demod uses [0..767]
    int b = blockIdx.x;
    int t = threadIdx.x;

    if (b < 64) {
        // ---- demod: d[n][co] = rsqrt(RC_W^2 * sum_ci s^2 * wsq + 1e-8) ----
        const float RCW2 = 1.0f / 4608.0f;
        int n   = b >> 3;
        int co0 = (b & 7) * 64;
        for (int i = t; i < CIN_; i += 256) { float v = s[n * CIN_ + i]; smem[i] = v * v; }
        __syncthreads();
        int col  = t & 63;
        int part = t >> 6;
        const float* wp = wsq + co0 + col;
        float a0 = 0.f, a1 = 0.f;
        int c0 = part * 128;
#pragma unroll 4
        for (int ci = c0; ci < c0 + 128; ci += 2) {
            a0 += smem[ci]     * wp[(size_t)ci * COUT_];
            a1 += smem[ci + 1] * wp[(size_t)(ci + 1) * COUT_];
        }
        smem[512 + part * 64 + col] = a0 + a1;
        __syncthreads();
        if (t < 64) {
            float r = smem[512 + t] + smem[576 + t] + smem[640 + t] + smem[704 + t];
            dmod[n * COUT_ + co0 + t] = rsqrtf(RCW2 * r + 1e-8f);
        }
    } else {
        int bb = b - 64;                 // n*32*66 + cb*66 + hp
        int hp = bb % 66;
        int cb = (bb / 66) % 32;
        int n  = bb / (66 * 32);
        int gh = hp - 1;
        bool rowok = (gh >= 0) && (gh < HH_);

        if (t < 16) smem[16 * 67 + t] = s[n * CIN_ + cb * 16 + t];
        if (rowok) {
            // 16 ci x 16 float4 = 256 threads, one float4 each (coalesced 256B/row)
            const float* src = &x[(((size_t)n * CIN_ + cb * 16) * HH_ + gh) * WW_];
            int ci = t >> 4;
            int g0 = (t & 15) * 4;
            float4 v = *(const float4*)&src[(size_t)ci * (HH_ * WW_) + g0];
            float* dstl = &smem[ci * 67 + g0];
            dstl[0] = v.x; dstl[1] = v.y; dstl[2] = v.z; dstl[3] = v.w;
        }
        __syncthreads();

        unsigned short* dst = xt + (((size_t)(n * 32 + cb) * 66 + hp) * 66) * 16;
        // 1056 u16 = 264 ushort4, 8B/lane coalesced stores
        for (int p = t; p < 264; p += 256) {
            int e   = p * 4;
            int wp_ = e >> 4;
            int cie = e & 15;       // 0,4,8,12
            int gw  = wp_ - 1;
            float vv0 = 0.f, vv1 = 0.f, vv2 = 0.f, vv3 = 0.f;
            if (rowok && gw >= 0 && gw < WW_) {
                vv0 = smem[(cie + 0) * 67 + gw] * smem[16 * 67 + cie + 0];
                vv1 = smem[(cie + 1) * 67 + gw] * smem[16 * 67 + cie + 1];
                vv2 = smem[(cie + 2) * 67 + gw] * smem[16 * 67 + cie + 2];
                vv3 = smem[(cie + 3) * 67 + gw] * smem[16 * 67 + cie + 3];
            }
            ushort4 o4;
            o4.x = f2bf(vv0); o4.y = f2bf(vv1); o4.z = f2bf(vv2); o4.w = f2bf(vv3);
            *(ushort4*)&dst[e] = o4;
        }
    }
}

// ============ main conv: implicit GEMM on 32x32x16 bf16 MFMA (unchanged from R1)
// block: M=128 spatial (8 rows x 16 cols patch), N=128 co; 4 waves, each 64x64.
// Staging via global_load_lds width=16 (async DMA, linear LDS dests).
__global__ __launch_bounds__(256) void conv_mfma(
    const unsigned short* __restrict__ xt,
    const unsigned short* __restrict__ wb,
    const float* __restrict__ dmod,
    float* __restrict__ out)
{
    __shared__ __align__(16) union {
        struct { unsigned short xs[2880]; unsigned short ws[18432]; } s;  // 42624 B
        float o[64 * 129];                                                // 33024 B
    } sm;

    int b   = blockIdx.x;
    int cot = b & 3;
    int wt_ = (b >> 2) & 3;
    int ht  = (b >> 4) & 7;
    int n   = b >> 7;
    int h0 = ht * 8, w0 = wt_ * 16, co0 = cot * 128;

    int t    = threadIdx.x;
    int wv   = t >> 6, lane = t & 63;
    int mh   = wv >> 1, nh = wv & 1;
    int l5   = lane & 31, half = lane >> 5;

    f32x16 acc[2][2];
#pragma unroll
    for (int ms = 0; ms < 2; ++ms)
#pragma unroll
        for (int ns = 0; ns < 2; ++ns)
#pragma unroll
            for (int i = 0; i < 16; ++i) acc[ms][ns][i] = 0.f;

    for (int cb = 0; cb < 32; ++cb) {
        // stage x halo tile: 10 rows x 18 wp x 16 ci (360 x 16B), async to LDS.
        const unsigned short* xb = xt + (((size_t)(n * 32 + cb) * 66 + h0) * 66 + w0) * 16;
        for (int li = t; li < 360; li += 256) {
            int row = li / 36;
            int off = li - row * 36;
            gl_lds16(&xb[row * 1056 + off * 8], &sm.s.xs[(li - lane) * 8]);
        }
        // stage weights: 9 taps x 128 co x 16 ci (each tap = 256 x 16B), async.
        const unsigned short* wbb = wb + ((size_t)cb * 512 + co0) * 16;
#pragma unroll
        for (int tap = 0; tap < 9; ++tap) {
            gl_lds16(&wbb[(size_t)tap * 32 * 512 * 16 + t * 8],
                     &sm.s.ws[tap * 2048 + wv * 512]);
        }
        __syncthreads();   // compiler emits s_waitcnt vmcnt(0) before s_barrier

#pragma unroll
        for (int tap = 0; tap < 9; ++tap) {
            int kh = tap / 3, kw = tap - 3 * (tap / 3);
            bf16x8v bfr[2], afr[2];
#pragma unroll
            for (int ns = 0; ns < 2; ++ns) {
                int co_l = nh * 64 + ns * 32 + l5;
                bfr[ns] = *(const bf16x8v*)&sm.s.ws[tap * 2048 + co_l * 16 + half * 8];
            }
#pragma unroll
            for (int ms = 0; ms < 2; ++ms) {
                int pr = mh * 4 + ms * 2 + (l5 >> 4);
                int pc = l5 & 15;
                int pos = (pr + kh) * 18 + (pc + kw);
                afr[ms] = *(const bf16x8v*)&sm.s.xs[pos * 16 + half * 8];
            }
#pragma unroll
            for (int ms = 0; ms < 2; ++ms)
#pragma unroll
                for (int ns = 0; ns < 2; ++ns)
                    acc[ms][ns] = __builtin_amdgcn_mfma_f32_32x32x16_bf16(
                        afr[ms], bfr[ns], acc[ms][ns], 0, 0, 0);
        }
        __syncthreads();
    }

    // epilogue: demod + LDS transpose + coalesced float4 stores (2 passes)
    for (int p = 0; p < 2; ++p) {
        __syncthreads();
        int co_l = nh * 64 + p * 32 + l5;
        int bco  = nh * 32 + l5;
        float dv = dmod[n * COUT_ + co0 + co_l];
#pragma unroll
        for (int ms = 0; ms < 2; ++ms) {
#pragma unroll
            for (int reg = 0; reg < 16; ++reg) {
                int ml = (reg & 3) + 8 * (reg >> 2) + 4 * half;
                int pr = mh * 4 + ms * 2 + (ml >> 4);
                int pc = ml & 15;
                sm.o[bco * 129 + pr * 16 + pc] = acc[ms][p][reg] * dv;
            }
        }
        __syncthreads();
        for (int j = t; j < 2048; j += 256) {
            int wq = j & 3;
            int pairidx = j >> 2;
            int row  = pairidx & 7;
            int bco2 = pairidx >> 3;
            int co = (bco2 >> 5) * 64 + p * 32 + (bco2 & 31);
            const float* src = &sm.o[bco2 * 129 + row * 16 + wq * 4];
            float4 v = make_float4(src[0], src[1], src[2], src[3]);
            *(float4*)&out[(((size_t)n * COUT_ + co0 + co) * HH_ + h0 + row) * WW_ + w0 + wq * 4] = v;
        }
    }
}

extern "C" void kernel_launch(void* const* d_in, const int* in_sizes, int n_in,
                              void* d_out, int out_size, void* d_ws, size_t ws_size,
                              hipStream_t stream) {
    const float* x    = (const float*)d_in[0];
    const float* dlat = (const float*)d_in[1];
    const float* w    = (const float*)d_in[2];
    const float* mw   = (const float*)d_in[3];
    const float* mb   = (const float*)d_in[4];
    float* out = (float*)d_out;

    char* ws = (char*)d_ws;
    float* s    = (float*)(ws);                       // 4096 f
    float* dmod = (float*)(ws + 16384);               // 4096 f
    float* wsq  = (float*)(ws + 32768);               // 262144 f
    unsigned short* xt = (unsigned short*)(ws + 1081344);    // 17,842,176 u16
    unsigned short* wb = (unsigned short*)(ws + 36765696);   // 2,359,296 u16

    prep1<<<1376, 256, 0, stream>>>(w, dlat, mw, mb, wsq, wb, s);
    prep2<<<64 + NB_ * 32 * 66, 256, 0, stream>>>(x, s, wsq, dmod, xt);
    conv_mfma<<<1024, 256, 0, stream>>>(xt, wb, dmod, out);
}

// Round 3
// 262.458 us; speedup vs baseline: 1.2535x; 1.1141x over previous
//
#include <hip/hip_runtime.h>
#include <math.h>

#define CIN_    512
#define COUT_   512
#define LATENT_ 512
#define NB_     8
#define HH_     64
#define WW_     64

typedef float f32x16 __attribute__((ext_vector_type(16)));
typedef short bf16x8v __attribute__((ext_vector_type(8)));

__device__ inline unsigned short f2bf(float f) {
    union { float f; unsigned u; } v; v.f = f;
    unsigned r = v.u + 0x7fffu + ((v.u >> 16) & 1u);
    return (unsigned short)(r >> 16);
}

// Async global->LDS 16B copy. LDS dest must be wave-uniform base; HW adds lane*16.
__device__ __forceinline__ void gl_lds16(const void* g, void* l) {
    __builtin_amdgcn_global_load_lds(
        (const __attribute__((address_space(1))) unsigned int*)g,
        (__attribute__((address_space(3))) unsigned int*)l,
        16, 0, 0);
}

// ============ K1: fused wsq (blocks 0..1023) + wprep (1024..1311) + style (1312..1375)
__global__ __launch_bounds__(256) void prep1(
    const float* __restrict__ w, const float* __restrict__ dlat,
    const float* __restrict__ mw, const float* __restrict__ mb,
    float* __restrict__ wsq, unsigned short* __restrict__ wb,
    float* __restrict__ s)
{
    __shared__ float smem[16 * 521];   // wprep transpose buffer; style reuses [0..767]
    const float RC_W = 0.0147313912747197f;   // 1/sqrt(9*512)
    const float RC_S = 0.0441941738241592f;   // 1/sqrt(512)
    int b = blockIdx.x;
    int t = threadIdx.x;

    if (b < 1024) {
        // ---- wsq[ci][co] = sum_tap w^2 (fp32, exact demod) ----
        int idx = b * 256 + t;
        float acc = 0.f;
#pragma unroll
        for (int tap = 0; tap < 9; ++tap) {
            float v = w[tap * (CIN_ * COUT_) + idx];
            acc += v * v;
        }
        wsq[idx] = acc;
    } else if (b < 1312) {
        // ---- wprep: wb[tap][cb][co 512][ci16] = w[tap][ci][co]*RC_W (bf16, transposed)
        int bb  = b - 1024;
        int tap = bb / 32;
        int cb  = bb % 32;
        for (int idx = t; idx < 16 * 512; idx += 256) {
            int ci = idx >> 9;
            int co = idx & 511;
            smem[ci * 521 + co] = w[((size_t)tap * 512 + cb * 16 + ci) * 512 + co];
        }
        __syncthreads();
        unsigned short* dst = wb + (size_t)(tap * 32 + cb) * 512 * 16;
        for (int idx = t; idx < 16 * 512; idx += 256) {
            int co = idx >> 4;
            int ci = idx & 15;
            dst[idx] = f2bf(smem[ci * 521 + co] * RC_W);
        }
    } else {
        // ---- style: s[n][ci] = dlat . (mw*RC_S) + mb + 1 ----
        // 64 blocks: n = bb>>3, ci-chunk of 64 = bb&7. 4 waves x 128-L slices.
        int bb  = b - 1312;
        int n   = bb >> 3;
        int ci0 = (bb & 7) * 64;
        for (int i = t; i < LATENT_; i += 256) smem[i] = dlat[n * LATENT_ + i];
        __syncthreads();
        int cil  = t & 63;          // ci within chunk (coalesced across lanes)
        int part = t >> 6;          // wave id: L-slice
        const float* mwp = mw + ci0 + cil;
        float a0 = 0.f, a1 = 0.f;
        int l0 = part * 128;
#pragma unroll 4
        for (int l = l0; l < l0 + 128; l += 2) {
            a0 += smem[l]     * mwp[(size_t)l * CIN_];
            a1 += smem[l + 1] * mwp[(size_t)(l + 1) * CIN_];
        }
        smem[512 + part * 64 + cil] = a0 + a1;
        __syncthreads();
        if (t < 64) {
            float r = smem[512 + t] + smem[576 + t] + smem[640 + t] + smem[704 + t];
            s[n * CIN_ + ci0 + t] = r * RC_S + mb[ci0 + t] + 1.0f;
        }
    }
}

// ============ K2: fused demod (blocks 0..63) + xprep (64..16959)
__global__ __launch_bounds__(256) void prep2(
    const float* __restrict__ x, const float* __restrict__ s,
    const float* __restrict__ wsq, float* __restrict__ dmod,
    unsigned short* __restrict__ xt)
{
    __shared__ float smem[16 * 67 + 16];   // 1088 floats; demod uses [0..767]
    int b = blockIdx.x;
    int t = threadIdx.x;

    if (b < 64) {
        // ---- demod: d[n][co] = rsqrt(RC_W^2 * sum_ci s^2 * wsq + 1e-8) ----
        const float RCW2 = 1.0f / 4608.0f;
        int n   = b >> 3;
        int co0 = (b & 7) * 64;
        for (int i = t; i < CIN_; i += 256) { float v = s[n * CIN_ + i]; smem[i] = v * v; }
        __syncthreads();
        int col  = t & 63;
        int part = t >> 6;
        const float* wp = wsq + co0 + col;
        float a0 = 0.f, a1 = 0.f;
        int c0 = part * 128;
#pragma unroll 4
        for (int ci = c0; ci < c0 + 128; ci += 2) {
            a0 += smem[ci]     * wp[(size_t)ci * COUT_];
            a1 += smem[ci + 1] * wp[(size_t)(ci + 1) * COUT_];
        }
        smem[512 + part * 64 + col] = a0 + a1;
        __syncthreads();
        if (t < 64) {
            float r = smem[512 + t] + smem[576 + t] + smem[640 + t] + smem[704 + t];
            dmod[n * COUT_ + co0 + t] = rsqrtf(RCW2 * r + 1e-8f);
        }
    } else {
        int bb = b - 64;                 // n*32*66 + cb*66 + hp
        int hp = bb % 66;
        int cb = (bb / 66) % 32;
        int n  = bb / (66 * 32);
        int gh = hp - 1;
        bool rowok = (gh >= 0) && (gh < HH_);

        if (t < 16) smem[16 * 67 + t] = s[n * CIN_ + cb * 16 + t];
        if (rowok) {
            const float* src = &x[(((size_t)n * CIN_ + cb * 16) * HH_ + gh) * WW_];
            int ci = t >> 4;
            int g0 = (t & 15) * 4;
            float4 v = *(const float4*)&src[(size_t)ci * (HH_ * WW_) + g0];
            float* dstl = &smem[ci * 67 + g0];
            dstl[0] = v.x; dstl[1] = v.y; dstl[2] = v.z; dstl[3] = v.w;
        }
        __syncthreads();

        unsigned short* dst = xt + (((size_t)(n * 32 + cb) * 66 + hp) * 66) * 16;
        for (int p = t; p < 264; p += 256) {
            int e   = p * 4;
            int wp_ = e >> 4;
            int cie = e & 15;       // 0,4,8,12
            int gw  = wp_ - 1;
            float vv0 = 0.f, vv1 = 0.f, vv2 = 0.f, vv3 = 0.f;
            if (rowok && gw >= 0 && gw < WW_) {
                vv0 = smem[(cie + 0) * 67 + gw] * smem[16 * 67 + cie + 0];
                vv1 = smem[(cie + 1) * 67 + gw] * smem[16 * 67 + cie + 1];
                vv2 = smem[(cie + 2) * 67 + gw] * smem[16 * 67 + cie + 2];
                vv3 = smem[(cie + 3) * 67 + gw] * smem[16 * 67 + cie + 3];
            }
            ushort4 o4;
            o4.x = f2bf(vv0); o4.y = f2bf(vv1); o4.z = f2bf(vv2); o4.w = f2bf(vv3);
            *(ushort4*)&dst[e] = o4;
        }
    }
}

// ============ main conv: implicit GEMM on 32x32x16 bf16 MFMA
// R3: N-tile 128 -> 256 per block, acc[2][4] per wave (64M x 128N).
// LDS read per MFMA drops 1KB -> 0.75KB; x-staging redundancy halves.
// 512 blocks x 256 thr; LDS 79.5KB -> 2 blocks/CU; launch_bounds caps VGPR<=256.
__global__ __launch_bounds__(256, 2) void conv_mfma(
    const unsigned short* __restrict__ xt,
    const unsigned short* __restrict__ wb,
    const float* __restrict__ dmod,
    float* __restrict__ out)
{
    __shared__ __align__(16) union {
        struct { unsigned short xs[2880]; unsigned short ws[36864]; } s;  // 79488 B
        float o[64 * 129];                                                // 33024 B
    } sm;

    int b   = blockIdx.x;
    int cot = b & 1;              // 2 co tiles of 256
    int wt_ = (b >> 1) & 3;
    int ht  = (b >> 3) & 7;
    int n   = b >> 6;
    int h0 = ht * 8, w0 = wt_ * 16, co0 = cot * 256;

    int t    = threadIdx.x;
    int wv   = t >> 6, lane = t & 63;
    int mh   = wv >> 1, nh = wv & 1;     // 2M x 2N wave grid
    int l5   = lane & 31, half = lane >> 5;

    f32x16 acc[2][4];
#pragma unroll
    for (int ms = 0; ms < 2; ++ms)
#pragma unroll
        for (int ns = 0; ns < 4; ++ns)
#pragma unroll
            for (int i = 0; i < 16; ++i) acc[ms][ns][i] = 0.f;

    for (int cb = 0; cb < 32; ++cb) {
        // stage x halo tile: 10 rows x 18 wp x 16 ci (360 x 16B), async to LDS.
        const unsigned short* xb = xt + (((size_t)(n * 32 + cb) * 66 + h0) * 66 + w0) * 16;
        {
            int li = t;
            gl_lds16(&xb[(li / 36) * 1056 + (li % 36) * 8], &sm.s.xs[(li - lane) * 8]);
            li = t + 256;
            if (li < 360)
                gl_lds16(&xb[(li / 36) * 1056 + (li % 36) * 8], &sm.s.xs[(li - lane) * 8]);
        }
        // stage weights: 9 taps x 256 co x 16 ci (each tap = 512 x 16B chunks), async.
        // chunk c = (co,half): global u16 off = (co0+?)·16 linear in c; LDS linear too.
        const unsigned short* wbb = wb + ((size_t)cb * 512 + co0) * 16;
#pragma unroll
        for (int tap = 0; tap < 9; ++tap) {
            const unsigned short* tsrc = wbb + (size_t)tap * 32 * 512 * 16;
            gl_lds16(&tsrc[t * 8],         &sm.s.ws[tap * 4096 + wv * 512]);
            gl_lds16(&tsrc[(t + 256) * 8], &sm.s.ws[tap * 4096 + 2048 + wv * 512]);
        }
        __syncthreads();   // vmcnt(0) drain + barrier

#pragma unroll
        for (int tap = 0; tap < 9; ++tap) {
            int kh = tap / 3, kw = tap - 3 * (tap / 3);
            bf16x8v bfr[4], afr[2];
#pragma unroll
            for (int ns = 0; ns < 4; ++ns) {
                int co_l = nh * 128 + ns * 32 + l5;
                bfr[ns] = *(const bf16x8v*)&sm.s.ws[tap * 4096 + co_l * 16 + half * 8];
            }
#pragma unroll
            for (int ms = 0; ms < 2; ++ms) {
                int pr = mh * 4 + ms * 2 + (l5 >> 4);
                int pc = l5 & 15;
                int pos = (pr + kh) * 18 + (pc + kw);
                afr[ms] = *(const bf16x8v*)&sm.s.xs[pos * 16 + half * 8];
            }
#pragma unroll
            for (int ms = 0; ms < 2; ++ms)
#pragma unroll
                for (int ns = 0; ns < 4; ++ns)
                    acc[ms][ns] = __builtin_amdgcn_mfma_f32_32x32x16_bf16(
                        afr[ms], bfr[ns], acc[ms][ns], 0, 0, 0);
        }
        __syncthreads();
    }

    // epilogue: demod + LDS transpose + coalesced float4 stores, 4 passes of 64 co.
    // Pass p covers co [p*64, p*64+64); written by waves with nh == p>>1,
    // ns = (p&1)*2 + q, q in {0,1}.
    for (int p = 0; p < 4; ++p) {
        __syncthreads();
        if (nh == (p >> 1)) {
#pragma unroll
            for (int q = 0; q < 2; ++q) {
                int bco = q * 32 + l5;
                float dv = dmod[n * COUT_ + co0 + p * 64 + bco];
#pragma unroll
                for (int ms = 0; ms < 2; ++ms) {
#pragma unroll
                    for (int reg = 0; reg < 16; ++reg) {
                        int ml = (reg & 3) + 8 * (reg >> 2) + 4 * half;
                        int m  = mh * 64 + ms * 32 + ml;      // 0..127 spatial
                        sm.o[bco * 129 + m] = acc[ms][(p & 1) * 2 + q][reg] * dv;
                    }
                }
            }
        }
        __syncthreads();
        for (int j = t; j < 2048; j += 256) {
            int wq = j & 3;
            int pairidx = j >> 2;
            int row  = pairidx & 7;
            int bco2 = pairidx >> 3;          // 0..63
            int co = co0 + p * 64 + bco2;
            const float* src = &sm.o[bco2 * 129 + row * 16 + wq * 4];
            float4 v = make_float4(src[0], src[1], src[2], src[3]);
            *(float4*)&out[(((size_t)n * COUT_ + co) * HH_ + h0 + row) * WW_ + w0 + wq * 4] = v;
        }
    }
}

extern "C" void kernel_launch(void* const* d_in, const int* in_sizes, int n_in,
                              void* d_out, int out_size, void* d_ws, size_t ws_size,
                              hipStream_t stream) {
    const float* x    = (const float*)d_in[0];
    const float* dlat = (const float*)d_in[1];
    const float* w    = (const float*)d_in[2];
    const float* mw   = (const float*)d_in[3];
    const float* mb   = (const float*)d_in[4];
    float* out = (float*)d_out;

    char* ws = (char*)d_ws;
    float* s    = (float*)(ws);                       // 4096 f
    float* dmod = (float*)(ws + 16384);               // 4096 f
    float* wsq  = (float*)(ws + 32768);               // 262144 f
    unsigned short* xt = (unsigned short*)(ws + 1081344);    // 17,842,176 u16
    unsigned short* wb = (unsigned short*)(ws + 36765696);   // 2,359,296 u16

    prep1<<<1376, 256, 0, stream>>>(w, dlat, mw, mb, wsq, wb, s);
    prep2<<<64 + NB_ * 32 * 66, 256, 0, stream>>>(x, s, wsq, dmod, xt);
    conv_mfma<<<512, 256, 0, stream>>>(xt, wb, dmod, out);
}